// Round 2
// baseline (461.621 us; speedup 1.0000x reference)
//
#include <hip/hip_runtime.h>
#include <cstdint>
#include <cstddef>

#define IN_F 4096
#define OUT_F 11008
#define M_ROWS 4096
#define QZ_STRIDE (OUT_F / 8) /* 1376 */
#define NKT (IN_F / 64)       /* 64 K-tiles */

typedef __attribute__((ext_vector_type(4))) float f32x4;
typedef __attribute__((ext_vector_type(8))) __bf16 bf16x8;
typedef uint32_t u32;
typedef uint16_t u16;

__device__ __forceinline__ u16 f2bf(float f) {
  u32 u = __builtin_bit_cast(u32, f);
  u += 0x7FFFu + ((u >> 16) & 1u);
  return (u16)(u >> 16);
}

// ---------------- x fp32 -> bf16 ----------------
__global__ void conv_x_kernel(const float* __restrict__ x, u16* __restrict__ xb) {
  const int total4 = (M_ROWS * IN_F) / 4;
  for (int i = blockIdx.x * blockDim.x + threadIdx.x; i < total4;
       i += gridDim.x * blockDim.x) {
    float4 v = reinterpret_cast<const float4*>(x)[i];
    uint2 o;
    o.x = (u32)f2bf(v.x) | ((u32)f2bf(v.y) << 16);
    o.y = (u32)f2bf(v.z) | ((u32)f2bf(v.w) << 16);
    reinterpret_cast<uint2*>(xb)[i] = o;
  }
}

// ------- dequant qweight -> WT [OUT_F][IN_F] bf16 (transposed, K contiguous) -------
__global__ void dequant_kernel(const int* __restrict__ qw, const int* __restrict__ qz,
                               const float* __restrict__ sc, u16* __restrict__ wt) {
  const int nl = threadIdx.x & 31, rl = threadIdx.x >> 5;
  const int n = blockIdx.x * 32 + nl;
  const int r = blockIdx.y * 8 + rl; // qweight row -> k = 8r..8r+7
  const int g = r >> 4;              // k/128
  u32 q = (u32)qw[(size_t)r * OUT_F + n];
  const int z = (int)(((u32)qz[g * QZ_STRIDE + (n >> 3)] >> (4 * (n & 7))) & 15u);
  const float s = sc[g * OUT_F + n];
  u32 o[4];
#pragma unroll
  for (int e = 0; e < 4; ++e) {
    u16 lo = f2bf(s * (float)((int)((q >> (8 * e)) & 15u) - z));
    u16 hi = f2bf(s * (float)((int)((q >> (8 * e + 4)) & 15u) - z));
    o[e] = (u32)lo | ((u32)hi << 16);
  }
  *reinterpret_cast<uint4*>(wt + (size_t)n * IN_F + r * 8) =
      make_uint4(o[0], o[1], o[2], o[3]);
}

// =======================================================================
// 256x256 tile, BK=64, 8 waves (2M x 4N), counted-vmcnt phase schedule.
// LDS: A/B double-buffered [256][64] bf16, read-swizzled col^((row&7)<<4),
// staged by global_load_lds with inverse-swizzled per-lane global source.
// Half-tiles per K-tile: H1=B rows{0-63,128-191}, H2=B rows{64-127,192-255},
// H3=A rows{0-63,128-191}, H4=A rows{64-127,192-255}.
// Steady state iteration u (reads buf[cur], cur=u&1):
//   ph1: read A(mi0-3)+B(ni0-1); issue (u+1).H3 -> A[cur^1]; MFMA Q00
//   ph2: read B(ni2-3);          issue (u+1).H4 -> A[cur^1]; MFMA Q01
//   ph3: read A(mi4-7);          issue (u+2).H1 -> B[cur];   MFMA Q10
//   ph4:                         issue (u+2).H2 -> B[cur];   MFMA Q11
//        s_waitcnt vmcnt(4)  (leaves (u+2).H1,H2 in flight)
// B[cur] is fully consumed after ph2 (B frags register-cached), so the
// ph3/ph4 stages into it are race-free via the phase barriers.
// =======================================================================
__global__ __launch_bounds__(512, 2) void gemm256(
    const u16* __restrict__ xb, const u16* __restrict__ wt,
    const float* __restrict__ bias, float* __restrict__ out) {
  __shared__ u16 As[2][256 * 64];
  __shared__ u16 Bs[2][256 * 64];
  const int tid = threadIdx.x;
  const int lane = tid & 63, wid = tid >> 6;
  // bijective XCD swizzle: gridDim.x = 688, 688 % 8 == 0
  const int cpx = (int)gridDim.x >> 3;
  const int swz = ((int)blockIdx.x & 7) * cpx + ((int)blockIdx.x >> 3);
  const int m0 = (swz & 15) * 256, n0 = (swz >> 4) * 256;
  const int wr = wid >> 2, wc = wid & 3;
  const int frow = lane & 15, g = lane >> 4, f7 = lane & 7;
  const int lrow = lane >> 3, ls = lane & 7;

  // swizzled ds_read col offsets (u16 units), logical slot = kk*4|g, xor row&7
  const int colsw0 = ((g ^ f7) << 3);
  const int colsw1 = (((4 | g) ^ f7) << 3);
  const int arow = (wr * 128 + frow) * 64; // u16 row base, stride 64 u16 = 128B
  const int brow = (wc * 64 + frow) * 64;

  // staging: per-lane global base (row = +lrow, col slot inverse-swizzled)
  const u16* gA = xb + (size_t)(m0 + lrow) * IN_F + ((ls ^ lrow) << 3);
  const u16* gB = wt + (size_t)(n0 + lrow) * IN_F + ((ls ^ lrow) << 3);
  const int rsbase = (wid >> 2) * 128 + (wid & 3) * 16; // + j*8 + h*64

  f32x4 acc[8][4] = {};
  bf16x8 af[4][2], bf[4][2];

  auto stage = [&](u16* ldsb, const u16* gl, int u, int h) {
#pragma unroll
    for (int j = 0; j < 2; ++j) {
      const int rowstart = rsbase + j * 8 + h * 64;
      __builtin_amdgcn_global_load_lds(
          (__attribute__((address_space(1))) void*)(gl + (size_t)rowstart * IN_F + (size_t)u * 64),
          (__attribute__((address_space(3))) void*)(ldsb + rowstart * 64), 16, 0, 0);
    }
  };

  // ---- prologue: (0).H1,H2,H3,H4, (1).H1,H2 ; wait tile0 landed ----
  stage(Bs[0], gB, 0, 0);
  stage(Bs[0], gB, 0, 1);
  stage(As[0], gA, 0, 0);
  stage(As[0], gA, 0, 1);
  stage(Bs[1], gB, 1, 0);
  stage(Bs[1], gB, 1, 1);
  asm volatile("s_waitcnt vmcnt(4)" ::: "memory");
  __builtin_amdgcn_s_barrier();

  for (int u = 0; u < NKT; ++u) {
    const int cur = u & 1;
    const u16* Ac = As[cur];
    const u16* Bc = Bs[cur];
    const bool stA = (u + 1 < NKT);
    const bool stB = (u + 2 < NKT);

    // ---------------- phase 1: A(mi0-3), B(ni0-1); Q00 ----------------
#pragma unroll
    for (int mi = 0; mi < 4; ++mi) {
      af[mi][0] = *reinterpret_cast<const bf16x8*>(Ac + arow + mi * 1024 + colsw0);
      af[mi][1] = *reinterpret_cast<const bf16x8*>(Ac + arow + mi * 1024 + colsw1);
    }
#pragma unroll
    for (int ni = 0; ni < 2; ++ni) {
      bf[ni][0] = *reinterpret_cast<const bf16x8*>(Bc + brow + ni * 1024 + colsw0);
      bf[ni][1] = *reinterpret_cast<const bf16x8*>(Bc + brow + ni * 1024 + colsw1);
    }
    if (stA) stage(As[cur ^ 1], gA, u + 1, 0);
    __builtin_amdgcn_s_barrier();
    asm volatile("s_waitcnt lgkmcnt(0)" ::: "memory");
    __builtin_amdgcn_s_setprio(1);
#pragma unroll
    for (int mi = 0; mi < 4; ++mi)
#pragma unroll
      for (int ni = 0; ni < 2; ++ni) {
        acc[mi][ni] = __builtin_amdgcn_mfma_f32_16x16x32_bf16(af[mi][0], bf[ni][0], acc[mi][ni], 0, 0, 0);
        acc[mi][ni] = __builtin_amdgcn_mfma_f32_16x16x32_bf16(af[mi][1], bf[ni][1], acc[mi][ni], 0, 0, 0);
      }
    __builtin_amdgcn_s_setprio(0);
    __builtin_amdgcn_s_barrier();

    // ---------------- phase 2: B(ni2-3); Q01 ----------------
#pragma unroll
    for (int ni = 0; ni < 2; ++ni) {
      bf[2 + ni][0] = *reinterpret_cast<const bf16x8*>(Bc + brow + (2 + ni) * 1024 + colsw0);
      bf[2 + ni][1] = *reinterpret_cast<const bf16x8*>(Bc + brow + (2 + ni) * 1024 + colsw1);
    }
    if (stA) stage(As[cur ^ 1], gA, u + 1, 1);
    __builtin_amdgcn_s_barrier();
    asm volatile("s_waitcnt lgkmcnt(0)" ::: "memory");
    __builtin_amdgcn_s_setprio(1);
#pragma unroll
    for (int mi = 0; mi < 4; ++mi)
#pragma unroll
      for (int ni = 0; ni < 2; ++ni) {
        acc[mi][2 + ni] = __builtin_amdgcn_mfma_f32_16x16x32_bf16(af[mi][0], bf[2 + ni][0], acc[mi][2 + ni], 0, 0, 0);
        acc[mi][2 + ni] = __builtin_amdgcn_mfma_f32_16x16x32_bf16(af[mi][1], bf[2 + ni][1], acc[mi][2 + ni], 0, 0, 0);
      }
    __builtin_amdgcn_s_setprio(0);
    __builtin_amdgcn_s_barrier();

    // ---------------- phase 3: A(mi4-7); Q10 ----------------
#pragma unroll
    for (int mi = 0; mi < 4; ++mi) {
      af[mi][0] = *reinterpret_cast<const bf16x8*>(Ac + arow + (4 + mi) * 1024 + colsw0);
      af[mi][1] = *reinterpret_cast<const bf16x8*>(Ac + arow + (4 + mi) * 1024 + colsw1);
    }
    if (stB) stage(Bs[cur], gB, u + 2, 0);
    __builtin_amdgcn_s_barrier();
    asm volatile("s_waitcnt lgkmcnt(0)" ::: "memory");
    __builtin_amdgcn_s_setprio(1);
#pragma unroll
    for (int mi = 0; mi < 4; ++mi)
#pragma unroll
      for (int ni = 0; ni < 2; ++ni) {
        acc[4 + mi][ni] = __builtin_amdgcn_mfma_f32_16x16x32_bf16(af[mi][0], bf[ni][0], acc[4 + mi][ni], 0, 0, 0);
        acc[4 + mi][ni] = __builtin_amdgcn_mfma_f32_16x16x32_bf16(af[mi][1], bf[ni][1], acc[4 + mi][ni], 0, 0, 0);
      }
    __builtin_amdgcn_s_setprio(0);
    __builtin_amdgcn_s_barrier();

    // ---------------- phase 4: Q11; counted vmcnt ----------------
    if (stB) stage(Bs[cur], gB, u + 2, 1);
    __builtin_amdgcn_s_barrier();
    __builtin_amdgcn_s_setprio(1);
#pragma unroll
    for (int mi = 0; mi < 4; ++mi)
#pragma unroll
      for (int ni = 0; ni < 2; ++ni) {
        acc[4 + mi][2 + ni] = __builtin_amdgcn_mfma_f32_16x16x32_bf16(af[mi][0], bf[2 + ni][0], acc[4 + mi][2 + ni], 0, 0, 0);
        acc[4 + mi][2 + ni] = __builtin_amdgcn_mfma_f32_16x16x32_bf16(af[mi][1], bf[2 + ni][1], acc[4 + mi][2 + ni], 0, 0, 0);
      }
    __builtin_amdgcn_s_setprio(0);
    if (u < NKT - 2)
      asm volatile("s_waitcnt vmcnt(4)" ::: "memory");
    else
      asm volatile("s_waitcnt vmcnt(0)" ::: "memory");
    __builtin_amdgcn_s_barrier();
  }

  // ---------------- epilogue: C = acc + bias ----------------
  const int crow = (lane >> 4) * 4, ccol = lane & 15;
#pragma unroll
  for (int ni = 0; ni < 4; ++ni) {
    const int col = n0 + wc * 64 + ni * 16 + ccol;
    const float bv = bias[col];
#pragma unroll
    for (int mi = 0; mi < 8; ++mi) {
      const int rowb = m0 + wr * 128 + mi * 16 + crow;
#pragma unroll
      for (int r2 = 0; r2 < 4; ++r2)
        out[(size_t)(rowb + r2) * OUT_F + col] = acc[mi][ni][r2] + bv;
    }
  }
}

// ---------------- fused fallback (ws too small): round-1 128^2 kernel ----------------
__global__ __launch_bounds__(256, 2) void gemm_fused(
    const float* __restrict__ x, const int* __restrict__ qw,
    const int* __restrict__ qz, const float* __restrict__ sc,
    const float* __restrict__ bias, float* __restrict__ out) {
  __shared__ u16 As[128 * 64];
  __shared__ u16 Bs[128 * 64];
  const int tid = threadIdx.x;
  const int lane = tid & 63, wid = tid >> 6;
  const int bm = blockIdx.x & 31, bn = blockIdx.x >> 5;
  const int m0 = bm * 128, n0 = bn * 128;
  const int wr = wid >> 1, wc = wid & 1;
  const int frow = lane & 15, fk = (lane >> 4) * 8;
  f32x4 acc[4][4] = {};

  for (int kt = 0; kt < 64; ++kt) {
    const int k0 = kt * 64;
#pragma unroll
    for (int it = 0; it < 8; ++it) {
      int c = it * 256 + tid;
      int row = c >> 4, c4 = c & 15;
      float4 v = *reinterpret_cast<const float4*>(
          x + (size_t)(m0 + row) * IN_F + k0 + c4 * 4);
      uint2 o;
      o.x = (u32)f2bf(v.x) | ((u32)f2bf(v.y) << 16);
      o.y = (u32)f2bf(v.z) | ((u32)f2bf(v.w) << 16);
      *reinterpret_cast<uint2*>(As + row * 64 + c4 * 4) = o;
    }
    {
      int nl = tid & 127, rq = tid >> 7;
      int n = n0 + nl;
      int gq = k0 >> 7;
      int z = (int)(((u32)qz[gq * QZ_STRIDE + (n >> 3)] >> (4 * (n & 7))) & 15u);
      float s = sc[gq * OUT_F + n];
#pragma unroll
      for (int j = 0; j < 4; ++j) {
        int r = (k0 >> 3) + rq * 4 + j;
        u32 q = (u32)qw[(size_t)r * OUT_F + n];
        u32 o[4];
#pragma unroll
        for (int e = 0; e < 4; ++e) {
          u16 lo = f2bf(s * (float)((int)((q >> (8 * e)) & 15u) - z));
          u16 hi = f2bf(s * (float)((int)((q >> (8 * e + 4)) & 15u) - z));
          o[e] = (u32)lo | ((u32)hi << 16);
        }
        *reinterpret_cast<uint4*>(Bs + nl * 64 + (rq * 4 + j) * 8) =
            make_uint4(o[0], o[1], o[2], o[3]);
      }
    }
    __syncthreads();
#pragma unroll
    for (int kk = 0; kk < 64; kk += 32) {
      bf16x8 a[4], b[4];
#pragma unroll
      for (int mi = 0; mi < 4; ++mi)
        a[mi] = *reinterpret_cast<const bf16x8*>(As + (wr * 64 + mi * 16 + frow) * 64 + kk + fk);
#pragma unroll
      for (int ni = 0; ni < 4; ++ni)
        b[ni] = *reinterpret_cast<const bf16x8*>(Bs + (wc * 64 + ni * 16 + frow) * 64 + kk + fk);
#pragma unroll
      for (int mi = 0; mi < 4; ++mi)
#pragma unroll
        for (int ni = 0; ni < 4; ++ni)
          acc[mi][ni] = __builtin_amdgcn_mfma_f32_16x16x32_bf16(a[mi], b[ni], acc[mi][ni], 0, 0, 0);
    }
    __syncthreads();
  }
  const int crow = (lane >> 4) * 4, ccol = lane & 15;
#pragma unroll
  for (int mi = 0; mi < 4; ++mi) {
#pragma unroll
    for (int ni = 0; ni < 4; ++ni) {
      int col = n0 + wc * 64 + ni * 16 + ccol;
      float bv = bias[col];
      int rowb = m0 + wr * 64 + mi * 16 + crow;
#pragma unroll
      for (int r2 = 0; r2 < 4; ++r2)
        out[(size_t)(rowb + r2) * OUT_F + col] = acc[mi][ni][r2] + bv;
    }
  }
}

extern "C" void kernel_launch(void* const* d_in, const int* in_sizes, int n_in,
                              void* d_out, int out_size, void* d_ws, size_t ws_size,
                              hipStream_t stream) {
  const float* x = (const float*)d_in[0];
  const int* qw = (const int*)d_in[1];
  const float* sc = (const float*)d_in[2];
  const int* qz = (const int*)d_in[3];
  const float* bias = (const float*)d_in[4];
  float* out = (float*)d_out;

  const size_t xb_bytes = (size_t)M_ROWS * IN_F * 2;  // 32 MiB
  const size_t wt_bytes = (size_t)OUT_F * IN_F * 2;   // ~86 MiB

  if (ws_size >= xb_bytes + wt_bytes) {
    u16* xb = (u16*)d_ws;
    u16* wtp = (u16*)((char*)d_ws + xb_bytes);
    hipLaunchKernelGGL(conv_x_kernel, dim3(2048), dim3(256), 0, stream, x, xb);
    hipLaunchKernelGGL(dequant_kernel, dim3(OUT_F / 32, 512 / 8), dim3(256), 0,
                       stream, qw, qz, sc, wtp);
    hipLaunchKernelGGL(gemm256, dim3((M_ROWS / 256) * (OUT_F / 256)), dim3(512),
                       0, stream, xb, wtp, bias, out);
  } else {
    hipLaunchKernelGGL(gemm_fused, dim3(32 * 86), dim3(256), 0, stream, x, qw,
                       qz, sc, bias, out);
  }
}

// Round 3
// 416.688 us; speedup vs baseline: 1.1078x; 1.1078x over previous
//
#include <hip/hip_runtime.h>
#include <cstdint>
#include <cstddef>

#define IN_F 4096
#define OUT_F 11008
#define M_ROWS 4096
#define QZ_STRIDE (OUT_F / 8) /* 1376 */
#define NKT (IN_F / 64)       /* 64 K-tiles */

typedef __attribute__((ext_vector_type(4))) float f32x4;
typedef __attribute__((ext_vector_type(8))) __bf16 bf16x8;
typedef uint32_t u32;
typedef uint16_t u16;

__device__ __forceinline__ u16 f2bf(float f) {
  u32 u = __builtin_bit_cast(u32, f);
  u += 0x7FFFu + ((u >> 16) & 1u);
  return (u16)(u >> 16);
}

// ---------------- x fp32 -> bf16 ----------------
__global__ void conv_x_kernel(const float* __restrict__ x, u16* __restrict__ xb) {
  const int total4 = (M_ROWS * IN_F) / 4;
  for (int i = blockIdx.x * blockDim.x + threadIdx.x; i < total4;
       i += gridDim.x * blockDim.x) {
    float4 v = reinterpret_cast<const float4*>(x)[i];
    uint2 o;
    o.x = (u32)f2bf(v.x) | ((u32)f2bf(v.y) << 16);
    o.y = (u32)f2bf(v.z) | ((u32)f2bf(v.w) << 16);
    reinterpret_cast<uint2*>(xb)[i] = o;
  }
}

// ------- dequant qweight -> WT [OUT_F][IN_F] bf16 (transposed, K contiguous) -------
__global__ void dequant_kernel(const int* __restrict__ qw, const int* __restrict__ qz,
                               const float* __restrict__ sc, u16* __restrict__ wt) {
  const int nl = threadIdx.x & 31, rl = threadIdx.x >> 5;
  const int n = blockIdx.x * 32 + nl;
  const int r = blockIdx.y * 8 + rl; // qweight row -> k = 8r..8r+7
  const int g = r >> 4;              // k/128
  u32 q = (u32)qw[(size_t)r * OUT_F + n];
  const int z = (int)(((u32)qz[g * QZ_STRIDE + (n >> 3)] >> (4 * (n & 7))) & 15u);
  const float s = sc[g * OUT_F + n];
  u32 o[4];
#pragma unroll
  for (int e = 0; e < 4; ++e) {
    u16 lo = f2bf(s * (float)((int)((q >> (8 * e)) & 15u) - z));
    u16 hi = f2bf(s * (float)((int)((q >> (8 * e + 4)) & 15u) - z));
    o[e] = (u32)lo | ((u32)hi << 16);
  }
  *reinterpret_cast<uint4*>(wt + (size_t)n * IN_F + r * 8) =
      make_uint4(o[0], o[1], o[2], o[3]);
}

// =======================================================================
// 256x256 tile, BK=64, 8 waves (2M x 4N), counted-vmcnt phase schedule.
// LDS: A/B double-buffered [256][64] bf16, read-swizzled col^((row&7)<<4),
// staged by global_load_lds with inverse-swizzled per-lane global source.
// Half-tiles: H1/H2 = B halves, H3/H4 = A halves (16KB each, 2 loads/thread).
// Iteration u reads buf[cur] (cur = u&1) and stages the FULL tile u+2 into
// buf[cur] late in the iteration (2-iteration prefetch lead for BOTH A,B):
//   ph1: ds_read A(mi0-3)+B(ni0-1);              MFMA Q00
//   ph2: ds_read B(ni2-3);                       MFMA Q01
//   ph3: ds_read A(mi4-7); stage (u+2).B.H1;     MFMA Q10   [B(u) read done]
//   ph4: stage (u+2).B.H2, (u+2).A.H3, (u+2).A.H4; MFMA Q11 [A(u) read done]
//        s_waitcnt vmcnt(8)   -> tile u+1 landed; tile u+2 (8 loads) in flight
// Lead time per tile ~5-6 phases (>HBM latency). All stage targets are
// regions fully consumed earlier in the same iteration (barrier-ordered).
// =======================================================================
__global__ __launch_bounds__(512, 2) void gemm256(
    const u16* __restrict__ xb, const u16* __restrict__ wt,
    const float* __restrict__ bias, float* __restrict__ out) {
  __shared__ u16 As[2][256 * 64];
  __shared__ u16 Bs[2][256 * 64];
  const int tid = threadIdx.x;
  const int lane = tid & 63, wid = tid >> 6;
  // bijective XCD swizzle: gridDim.x = 688, 688 % 8 == 0
  const int cpx = (int)gridDim.x >> 3;
  const int swz = ((int)blockIdx.x & 7) * cpx + ((int)blockIdx.x >> 3);
  const int m0 = (swz & 15) * 256, n0 = (swz >> 4) * 256;
  const int wr = wid >> 2, wc = wid & 3;
  const int frow = lane & 15, g = lane >> 4, f7 = lane & 7;
  const int lrow = lane >> 3, ls = lane & 7;

  // swizzled ds_read col offsets (u16 units), logical slot = kk*4|g, xor row&7
  const int colsw0 = ((g ^ f7) << 3);
  const int colsw1 = (((4 | g) ^ f7) << 3);
  const int arow = (wr * 128 + frow) * 64; // u16 row base, stride 64 u16 = 128B
  const int brow = (wc * 64 + frow) * 64;

  // staging: per-lane global base (row = +lrow, col slot inverse-swizzled)
  const u16* gA = xb + (size_t)(m0 + lrow) * IN_F + ((ls ^ lrow) << 3);
  const u16* gB = wt + (size_t)(n0 + lrow) * IN_F + ((ls ^ lrow) << 3);
  const int rsbase = (wid >> 2) * 128 + (wid & 3) * 16; // + j*8 + h*64

  f32x4 acc[8][4] = {};
  bf16x8 af[4][2], bf[4][2];

  auto stage = [&](u16* ldsb, const u16* gl, int u, int h) {
#pragma unroll
    for (int j = 0; j < 2; ++j) {
      const int rowstart = rsbase + j * 8 + h * 64;
      __builtin_amdgcn_global_load_lds(
          (__attribute__((address_space(1))) void*)(gl + (size_t)rowstart * IN_F + (size_t)u * 64),
          (__attribute__((address_space(3))) void*)(ldsb + rowstart * 64), 16, 0, 0);
    }
  };

  // ---- prologue: full tile 0, full tile 1 (16 loads); wait tile 0 ----
  stage(Bs[0], gB, 0, 0);
  stage(Bs[0], gB, 0, 1);
  stage(As[0], gA, 0, 0);
  stage(As[0], gA, 0, 1);
  stage(Bs[1], gB, 1, 0);
  stage(Bs[1], gB, 1, 1);
  stage(As[1], gA, 1, 0);
  stage(As[1], gA, 1, 1);
  asm volatile("s_waitcnt vmcnt(8)" ::: "memory");
  __builtin_amdgcn_s_barrier();

  for (int u = 0; u < NKT; ++u) {
    const int cur = u & 1;
    const u16* Ac = As[cur];
    const u16* Bc = Bs[cur];
    const bool stT = (u + 2 < NKT);

    // ---------------- phase 1: A(mi0-3), B(ni0-1); Q00 ----------------
#pragma unroll
    for (int mi = 0; mi < 4; ++mi) {
      af[mi][0] = *reinterpret_cast<const bf16x8*>(Ac + arow + mi * 1024 + colsw0);
      af[mi][1] = *reinterpret_cast<const bf16x8*>(Ac + arow + mi * 1024 + colsw1);
    }
#pragma unroll
    for (int ni = 0; ni < 2; ++ni) {
      bf[ni][0] = *reinterpret_cast<const bf16x8*>(Bc + brow + ni * 1024 + colsw0);
      bf[ni][1] = *reinterpret_cast<const bf16x8*>(Bc + brow + ni * 1024 + colsw1);
    }
    __builtin_amdgcn_s_barrier();
    asm volatile("s_waitcnt lgkmcnt(0)" ::: "memory");
    __builtin_amdgcn_s_setprio(1);
#pragma unroll
    for (int mi = 0; mi < 4; ++mi)
#pragma unroll
      for (int ni = 0; ni < 2; ++ni) {
        acc[mi][ni] = __builtin_amdgcn_mfma_f32_16x16x32_bf16(af[mi][0], bf[ni][0], acc[mi][ni], 0, 0, 0);
        acc[mi][ni] = __builtin_amdgcn_mfma_f32_16x16x32_bf16(af[mi][1], bf[ni][1], acc[mi][ni], 0, 0, 0);
      }
    __builtin_amdgcn_s_setprio(0);
    __builtin_amdgcn_s_barrier();

    // ---------------- phase 2: B(ni2-3); Q01 ----------------
#pragma unroll
    for (int ni = 0; ni < 2; ++ni) {
      bf[2 + ni][0] = *reinterpret_cast<const bf16x8*>(Bc + brow + (2 + ni) * 1024 + colsw0);
      bf[2 + ni][1] = *reinterpret_cast<const bf16x8*>(Bc + brow + (2 + ni) * 1024 + colsw1);
    }
    __builtin_amdgcn_s_barrier();
    asm volatile("s_waitcnt lgkmcnt(0)" ::: "memory");
    __builtin_amdgcn_s_setprio(1);
#pragma unroll
    for (int mi = 0; mi < 4; ++mi)
#pragma unroll
      for (int ni = 0; ni < 2; ++ni) {
        acc[mi][2 + ni] = __builtin_amdgcn_mfma_f32_16x16x32_bf16(af[mi][0], bf[2 + ni][0], acc[mi][2 + ni], 0, 0, 0);
        acc[mi][2 + ni] = __builtin_amdgcn_mfma_f32_16x16x32_bf16(af[mi][1], bf[2 + ni][1], acc[mi][2 + ni], 0, 0, 0);
      }
    __builtin_amdgcn_s_setprio(0);
    __builtin_amdgcn_s_barrier();

    // ------- phase 3: A(mi4-7); stage (u+2).B.H1 -> Bs[cur]; Q10 -------
#pragma unroll
    for (int mi = 0; mi < 4; ++mi) {
      af[mi][0] = *reinterpret_cast<const bf16x8*>(Ac + arow + (4 + mi) * 1024 + colsw0);
      af[mi][1] = *reinterpret_cast<const bf16x8*>(Ac + arow + (4 + mi) * 1024 + colsw1);
    }
    if (stT) stage(Bs[cur], gB, u + 2, 0);
    __builtin_amdgcn_s_barrier();
    asm volatile("s_waitcnt lgkmcnt(0)" ::: "memory");
    __builtin_amdgcn_s_setprio(1);
#pragma unroll
    for (int mi = 0; mi < 4; ++mi)
#pragma unroll
      for (int ni = 0; ni < 2; ++ni) {
        acc[4 + mi][ni] = __builtin_amdgcn_mfma_f32_16x16x32_bf16(af[mi][0], bf[ni][0], acc[4 + mi][ni], 0, 0, 0);
        acc[4 + mi][ni] = __builtin_amdgcn_mfma_f32_16x16x32_bf16(af[mi][1], bf[ni][1], acc[4 + mi][ni], 0, 0, 0);
      }
    __builtin_amdgcn_s_setprio(0);
    __builtin_amdgcn_s_barrier();

    // ------- phase 4: stage (u+2).B.H2, A.H3, A.H4; Q11; vmcnt(8) -------
    if (stT) {
      stage(Bs[cur], gB, u + 2, 1);
      stage(As[cur], gA, u + 2, 0);
      stage(As[cur], gA, u + 2, 1);
    }
    __builtin_amdgcn_s_barrier();
    __builtin_amdgcn_s_setprio(1);
#pragma unroll
    for (int mi = 0; mi < 4; ++mi)
#pragma unroll
      for (int ni = 0; ni < 2; ++ni) {
        acc[4 + mi][2 + ni] = __builtin_amdgcn_mfma_f32_16x16x32_bf16(af[mi][0], bf[2 + ni][0], acc[4 + mi][2 + ni], 0, 0, 0);
        acc[4 + mi][2 + ni] = __builtin_amdgcn_mfma_f32_16x16x32_bf16(af[mi][1], bf[2 + ni][1], acc[4 + mi][2 + ni], 0, 0, 0);
      }
    __builtin_amdgcn_s_setprio(0);
    if (stT)
      asm volatile("s_waitcnt vmcnt(8)" ::: "memory");
    else
      asm volatile("s_waitcnt vmcnt(0)" ::: "memory");
    __builtin_amdgcn_s_barrier();
  }

  // ---------------- epilogue: C = acc + bias (nontemporal stores) ----------------
  const int crow = (lane >> 4) * 4, ccol = lane & 15;
#pragma unroll
  for (int ni = 0; ni < 4; ++ni) {
    const int col = n0 + wc * 64 + ni * 16 + ccol;
    const float bv = bias[col];
#pragma unroll
    for (int mi = 0; mi < 8; ++mi) {
      const int rowb = m0 + wr * 128 + mi * 16 + crow;
#pragma unroll
      for (int r2 = 0; r2 < 4; ++r2)
        __builtin_nontemporal_store(acc[mi][ni][r2] + bv,
                                    out + (size_t)(rowb + r2) * OUT_F + col);
    }
  }
}

// ---------------- fused fallback (ws too small): round-1 128^2 kernel ----------------
__global__ __launch_bounds__(256, 2) void gemm_fused(
    const float* __restrict__ x, const int* __restrict__ qw,
    const int* __restrict__ qz, const float* __restrict__ sc,
    const float* __restrict__ bias, float* __restrict__ out) {
  __shared__ u16 As[128 * 64];
  __shared__ u16 Bs[128 * 64];
  const int tid = threadIdx.x;
  const int lane = tid & 63, wid = tid >> 6;
  const int bm = blockIdx.x & 31, bn = blockIdx.x >> 5;
  const int m0 = bm * 128, n0 = bn * 128;
  const int wr = wid >> 1, wc = wid & 1;
  const int frow = lane & 15, fk = (lane >> 4) * 8;
  f32x4 acc[4][4] = {};

  for (int kt = 0; kt < 64; ++kt) {
    const int k0 = kt * 64;
#pragma unroll
    for (int it = 0; it < 8; ++it) {
      int c = it * 256 + tid;
      int row = c >> 4, c4 = c & 15;
      float4 v = *reinterpret_cast<const float4*>(
          x + (size_t)(m0 + row) * IN_F + k0 + c4 * 4);
      uint2 o;
      o.x = (u32)f2bf(v.x) | ((u32)f2bf(v.y) << 16);
      o.y = (u32)f2bf(v.z) | ((u32)f2bf(v.w) << 16);
      *reinterpret_cast<uint2*>(As + row * 64 + c4 * 4) = o;
    }
    {
      int nl = tid & 127, rq = tid >> 7;
      int n = n0 + nl;
      int gq = k0 >> 7;
      int z = (int)(((u32)qz[gq * QZ_STRIDE + (n >> 3)] >> (4 * (n & 7))) & 15u);
      float s = sc[gq * OUT_F + n];
#pragma unroll
      for (int j = 0; j < 4; ++j) {
        int r = (k0 >> 3) + rq * 4 + j;
        u32 q = (u32)qw[(size_t)r * OUT_F + n];
        u32 o[4];
#pragma unroll
        for (int e = 0; e < 4; ++e) {
          u16 lo = f2bf(s * (float)((int)((q >> (8 * e)) & 15u) - z));
          u16 hi = f2bf(s * (float)((int)((q >> (8 * e + 4)) & 15u) - z));
          o[e] = (u32)lo | ((u32)hi << 16);
        }
        *reinterpret_cast<uint4*>(Bs + nl * 64 + (rq * 4 + j) * 8) =
            make_uint4(o[0], o[1], o[2], o[3]);
      }
    }
    __syncthreads();
#pragma unroll
    for (int kk = 0; kk < 64; kk += 32) {
      bf16x8 a[4], b[4];
#pragma unroll
      for (int mi = 0; mi < 4; ++mi)
        a[mi] = *reinterpret_cast<const bf16x8*>(As + (wr * 64 + mi * 16 + frow) * 64 + kk + fk);
#pragma unroll
      for (int ni = 0; ni < 4; ++ni)
        b[ni] = *reinterpret_cast<const bf16x8*>(Bs + (wc * 64 + ni * 16 + frow) * 64 + kk + fk);
#pragma unroll
      for (int mi = 0; mi < 4; ++mi)
#pragma unroll
        for (int ni = 0; ni < 4; ++ni)
          acc[mi][ni] = __builtin_amdgcn_mfma_f32_16x16x32_bf16(a[mi], b[ni], acc[mi][ni], 0, 0, 0);
    }
    __syncthreads();
  }
  const int crow = (lane >> 4) * 4, ccol = lane & 15;
#pragma unroll
  for (int mi = 0; mi < 4; ++mi) {
#pragma unroll
    for (int ni = 0; ni < 4; ++ni) {
      int col = n0 + wc * 64 + ni * 16 + ccol;
      float bv = bias[col];
      int rowb = m0 + wr * 64 + mi * 16 + crow;
#pragma unroll
      for (int r2 = 0; r2 < 4; ++r2)
        out[(size_t)(rowb + r2) * OUT_F + col] = acc[mi][ni][r2] + bv;
    }
  }
}

extern "C" void kernel_launch(void* const* d_in, const int* in_sizes, int n_in,
                              void* d_out, int out_size, void* d_ws, size_t ws_size,
                              hipStream_t stream) {
  const float* x = (const float*)d_in[0];
  const int* qw = (const int*)d_in[1];
  const float* sc = (const float*)d_in[2];
  const int* qz = (const int*)d_in[3];
  const float* bias = (const float*)d_in[4];
  float* out = (float*)d_out;

  const size_t xb_bytes = (size_t)M_ROWS * IN_F * 2;  // 32 MiB
  const size_t wt_bytes = (size_t)OUT_F * IN_F * 2;   // ~86 MiB

  if (ws_size >= xb_bytes + wt_bytes) {
    u16* xb = (u16*)d_ws;
    u16* wtp = (u16*)((char*)d_ws + xb_bytes);
    hipLaunchKernelGGL(conv_x_kernel, dim3(2048), dim3(256), 0, stream, x, xb);
    hipLaunchKernelGGL(dequant_kernel, dim3(OUT_F / 32, 512 / 8), dim3(256), 0,
                       stream, qw, qz, sc, wtp);
    hipLaunchKernelGGL(gemm256, dim3((M_ROWS / 256) * (OUT_F / 256)), dim3(512),
                       0, stream, xb, wtp, bias, out);
  } else {
    hipLaunchKernelGGL(gemm_fused, dim3(32 * 86), dim3(256), 0, stream, x, qw,
                       qz, sc, bias, out);
  }
}